// Round 1
// baseline (4068.237 us; speedup 1.0000x reference)
//
#include <hip/hip_runtime.h>
#include <cstdint>
#include <cstddef>

// GAT: T=32 frames, N=512 nodes, Fh=256, H=8 heads, L=3 layers, Din=3.
// Strategy round 0: correctness-first fp32.
//  - CSR-ified adjacency (static, ~6% density + self loops) -> sparse softmax,
//    exactly equivalent to dense -9e15 masking (exp underflows to 0).
//  - Batched frames: M = TC*512 rows per GEMM; TC chosen to fit ws_size.

#define GTM 64
#define GTN 64
#define GTK 16

// ---------------- CSR build (ballot compaction, one wave per row) -------------
__global__ __launch_bounds__(256)
void build_csr_kernel(const int* __restrict__ adj, int* __restrict__ cnt,
                      int* __restrict__ idxout)
{
    int row  = blockIdx.x * 4 + (threadIdx.x >> 6);
    int lane = threadIdx.x & 63;
    if (row >= 512) return;
    int base = 0;
    for (int j0 = 0; j0 < 512; j0 += 64) {
        int j = j0 + lane;
        bool pred = adj[row * 512 + j] > 0;
        unsigned long long m = __ballot(pred);
        if (pred) {
            int pos = __popcll(m & ((1ull << lane) - 1ull));
            idxout[row * 512 + base + pos] = j;
        }
        base += __popcll(m);
    }
    if (lane == 0) cnt[row] = base;
}

// ---------------- generic fp32 GEMM: C[b] = A @ B[b] (+bias) -----------------
// A: [M,K] shared across batch; B: [K,N] (+ b*strideB); C: [M,N] (+ b*strideC)
// M % 64 == 0, N % 64 == 0 guaranteed by caller; K arbitrary.
__global__ __launch_bounds__(256)
void gemm_kernel(const float* __restrict__ A, const float* __restrict__ B,
                 float* __restrict__ C, const float* __restrict__ bias,
                 int M, int K, int N, long strideB, long strideC)
{
    int b = blockIdx.z;
    const float* Bb = B + (long)b * strideB;
    float* Cb = C + (long)b * strideC;
    int m0 = blockIdx.y * GTM;
    int n0 = blockIdx.x * GTN;

    __shared__ float As[GTK][GTM + 1];   // transposed store, +1 pad kills conflicts
    __shared__ float Bs[GTK][GTN];

    int tid = threadIdx.x;        // 256 threads
    int tx = tid & 15, ty = tid >> 4;
    float acc[4][4] = {};

    for (int k0 = 0; k0 < K; k0 += GTK) {
        #pragma unroll
        for (int e = 0; e < 4; e++) {          // A tile 64x16
            int idx = tid + e * 256;
            int m = idx >> 4, k = idx & 15;
            float v = 0.f;
            if (k0 + k < K) v = A[(long)(m0 + m) * K + k0 + k];
            As[k][m] = v;
        }
        #pragma unroll
        for (int e = 0; e < 4; e++) {          // B tile 16x64
            int idx = tid + e * 256;
            int k = idx >> 6, n = idx & 63;
            float v = 0.f;
            if (k0 + k < K) v = Bb[(long)(k0 + k) * N + n0 + n];
            Bs[k][n] = v;
        }
        __syncthreads();
        #pragma unroll
        for (int kk = 0; kk < GTK; kk++) {
            float av[4], bv[4];
            #pragma unroll
            for (int i = 0; i < 4; i++) av[i] = As[kk][ty * 4 + i];
            #pragma unroll
            for (int j = 0; j < 4; j++) bv[j] = Bs[kk][tx * 4 + j];
            #pragma unroll
            for (int i = 0; i < 4; i++)
                #pragma unroll
                for (int j = 0; j < 4; j++)
                    acc[i][j] = fmaf(av[i], bv[j], acc[i][j]);
        }
        __syncthreads();
    }
    #pragma unroll
    for (int i = 0; i < 4; i++) {
        int m = m0 + ty * 4 + i;
        #pragma unroll
        for (int j = 0; j < 4; j++) {
            int n = n0 + tx * 4 + j;
            float v = acc[i][j];
            if (bias) v += bias[n];
            Cb[(long)m * N + n] = v;
        }
    }
}

// ---------------- f/g = Wh @ a1, Wh @ a2 (one wave per row) ------------------
__global__ __launch_bounds__(256)
void fg_kernel(const float* __restrict__ WhAll, const float* __restrict__ aAll,
               float* __restrict__ fAll, float* __restrict__ gAll,
               int R, long aStride)
{
    int h = blockIdx.y;
    int row = blockIdx.x * 4 + (threadIdx.x >> 6);
    int lane = threadIdx.x & 63;
    if (row >= R) return;
    const float* wh = WhAll + (long)h * R * 256 + (long)row * 256;
    const float* a = aAll + (long)h * aStride;
    float sf = 0.f, sg = 0.f;
    #pragma unroll
    for (int k = lane; k < 256; k += 64) {
        float v = wh[k];
        sf = fmaf(v, a[k], sf);
        sg = fmaf(v, a[256 + k], sg);
    }
    #pragma unroll
    for (int off = 32; off > 0; off >>= 1) {
        sf += __shfl_down(sf, off);
        sg += __shfl_down(sg, off);
    }
    if (lane == 0) {
        fAll[(long)h * R + row] = sf;
        gAll[(long)h * R + row] = sg;
    }
}

// ---------------- sparse GAT attention row: softmax + weighted sum + elu -----
// block = (node i, frame t, head h); 256 threads; thread tid owns feature tid.
__global__ __launch_bounds__(256)
void attn_kernel(const float* __restrict__ WhAll, const float* __restrict__ fAll,
                 const float* __restrict__ gAll,
                 const int* __restrict__ nbr_cnt, const int* __restrict__ nbr_idx,
                 float* __restrict__ out, int outStride, int headStrideOut,
                 int R, int doubleElu)
{
    int i = blockIdx.x;
    int t = blockIdx.y;
    int h = blockIdx.z;
    const float* Wh = WhAll + (long)h * R * 256;
    const float* f = fAll + (long)h * R;
    const float* g = gAll + (long)h * R;
    int row = t * 512 + i;

    __shared__ float p[512];
    __shared__ int nid[512];
    __shared__ float red[256];

    int tid = threadIdx.x;
    int c = nbr_cnt[i];
    float fi = f[row];

    for (int j = tid; j < c; j += 256) {
        int nj = nbr_idx[i * 512 + j];
        nid[j] = nj;
        float e = fi + g[t * 512 + nj];
        p[j] = e >= 0.f ? e : 0.2f * e;   // leaky_relu(0.2)
    }
    __syncthreads();

    float lm = -3.4e38f;
    for (int j = tid; j < c; j += 256) lm = fmaxf(lm, p[j]);
    red[tid] = lm; __syncthreads();
    #pragma unroll
    for (int s = 128; s > 0; s >>= 1) {
        if (tid < s) red[tid] = fmaxf(red[tid], red[tid + s]);
        __syncthreads();
    }
    float m = red[0];
    __syncthreads();

    float ls = 0.f;
    for (int j = tid; j < c; j += 256) {
        float e = expf(p[j] - m);
        p[j] = e;
        ls += e;
    }
    red[tid] = ls; __syncthreads();
    #pragma unroll
    for (int s = 128; s > 0; s >>= 1) {
        if (tid < s) red[tid] += red[tid + s];
        __syncthreads();
    }
    float inv = 1.f / red[0];
    __syncthreads();

    // weighted sum over neighbors; feature = tid (coalesced per j)
    float acc = 0.f;
    for (int j = 0; j < c; j++) {
        acc = fmaf(p[j], Wh[(long)(t * 512 + nid[j]) * 256 + tid], acc);
    }
    acc *= inv;
    float o = acc > 0.f ? acc : expm1f(acc);          // elu
    if (doubleElu) o = o > 0.f ? o : expm1f(o);       // outer elu (out-gat)
    out[(long)row * outStride + h * headStrideOut + tid] = o;
}

// ---------------- mean over nodes ----------------
__global__ __launch_bounds__(256)
void pool_kernel(const float* __restrict__ x, float* __restrict__ pooled)
{
    int t = blockIdx.x, col = threadIdx.x;
    float s = 0.f;
    for (int n = 0; n < 512; n++) s += x[(long)(t * 512 + n) * 256 + col];
    pooled[t * 256 + col] = s * (1.f / 512.f);
}

// ---------------- final: out = pooled @ Wo + bo ----------------
__global__ __launch_bounds__(256)
void final_kernel(const float* __restrict__ pooled, const float* __restrict__ Wo,
                  const float* __restrict__ bo, float* __restrict__ out)
{
    int t = blockIdx.x, c = threadIdx.x;
    float s = bo[c];
    for (int k = 0; k < 256; k++) s = fmaf(pooled[t * 256 + k], Wo[k * 256 + c], s);
    out[t * 256 + c] = s;
}

extern "C" void kernel_launch(void* const* d_in, const int* in_sizes, int n_in,
                              void* d_out, int out_size, void* d_ws, size_t ws_size,
                              hipStream_t stream)
{
    const float* pose   = (const float*)d_in[0];   // [32,512,3]
    const int*   adj    = (const int*)  d_in[1];   // [512,512]
    const float* Wp     = (const float*)d_in[2];   // [3,256]
    const float* bp     = (const float*)d_in[3];   // [256]
    const float* Wh_w   = (const float*)d_in[4];   // [3,8,256,256]
    const float* a_h    = (const float*)d_in[5];   // [3,8,512]
    const float* W_outw = (const float*)d_in[6];   // [3,2048,256]
    const float* a_o    = (const float*)d_in[7];   // [3,512]
    const float* Wo     = (const float*)d_in[8];   // [256,256]
    const float* bo     = (const float*)d_in[9];   // [256]
    float* out = (float*)d_out;                    // [32,256]

    const int T = 32, N = 512, F = 256, H = 8, L = 3, Din = 3;

    // pick largest frame-chunk TC that fits workspace
    auto need = [&](int TC) -> size_t {
        size_t R = (size_t)TC * N;
        size_t b = 0;
        b += ((R * F * 4 + 255) & ~(size_t)255);                 // x
        b += ((R * (size_t)H * F * 4 + 255) & ~(size_t)255);     // xcat
        b += (((size_t)H * R * F * 4 + 255) & ~(size_t)255);     // WhAll
        b += 2 * (((size_t)H * R * 4 + 255) & ~(size_t)255);     // f,g
        b += (((size_t)TC * F * 4 + 255) & ~(size_t)255);        // pooled
        b += ((512 * 4 + 255) & ~(size_t)255);                   // nbr_cnt
        b += ((512 * 512 * 4 + 255) & ~(size_t)255);             // nbr_idx
        return b + 1024;
    };
    int TC = 32;
    while (TC > 1 && need(TC) > ws_size) TC >>= 1;
    size_t R = (size_t)TC * N;

    char* wp = (char*)d_ws;
    auto alloc = [&](size_t bytes) -> char* {
        char* r = wp; wp += (bytes + 255) & ~(size_t)255; return r;
    };
    float* x      = (float*)alloc(R * F * 4);
    float* xcat   = (float*)alloc(R * (size_t)H * F * 4);
    float* WhAll  = (float*)alloc((size_t)H * R * F * 4);
    float* fAll   = (float*)alloc((size_t)H * R * 4);
    float* gAll   = (float*)alloc((size_t)H * R * 4);
    float* pooled = (float*)alloc((size_t)TC * F * 4);
    int*   ncnt   = (int*)alloc(512 * 4);
    int*   nidx   = (int*)alloc(512 * 512 * 4);

    build_csr_kernel<<<128, 256, 0, stream>>>(adj, ncnt, nidx);

    for (int t0 = 0; t0 < T; t0 += TC) {
        // input projection: x = pose_chunk @ Wp + bp
        gemm_kernel<<<dim3(F / 64, (unsigned)(R / 64), 1), 256, 0, stream>>>(
            pose + (size_t)t0 * N * Din, Wp, x, bp, (int)R, Din, F, 0, 0);

        for (int l = 0; l < L; l++) {
            // per-head Wh = x @ W_heads[l,h]   (batched over heads)
            gemm_kernel<<<dim3(F / 64, (unsigned)(R / 64), H), 256, 0, stream>>>(
                x, Wh_w + (size_t)l * H * F * F, WhAll, nullptr, (int)R, F, F,
                (long)F * F, (long)R * F);
            fg_kernel<<<dim3((unsigned)(R / 4), H), 256, 0, stream>>>(
                WhAll, a_h + (size_t)l * H * 2 * F, fAll, gAll, (int)R, 2 * F);
            // head attention -> xcat[:, h*256:(h+1)*256], elu
            attn_kernel<<<dim3(N, TC, H), 256, 0, stream>>>(
                WhAll, fAll, gAll, ncnt, nidx, xcat, H * F, F, (int)R, 0);
            // out-gat: Wh_o = xcat @ W_out[l]  (reuse WhAll slab 0)
            gemm_kernel<<<dim3(F / 64, (unsigned)(R / 64), 1), 256, 0, stream>>>(
                xcat, W_outw + (size_t)l * H * F * F, WhAll, nullptr, (int)R, H * F, F, 0, 0);
            fg_kernel<<<dim3((unsigned)(R / 4), 1), 256, 0, stream>>>(
                WhAll, a_o + (size_t)l * 2 * F, fAll, gAll, (int)R, 2 * F);
            // out attention -> x, elu applied twice
            attn_kernel<<<dim3(N, TC, 1), 256, 0, stream>>>(
                WhAll, fAll, gAll, ncnt, nidx, x, F, 0, (int)R, 1);
        }
        pool_kernel<<<TC, 256, 0, stream>>>(x, pooled);
        final_kernel<<<TC, 256, 0, stream>>>(pooled, Wo, bo, out + (size_t)t0 * F);
    }
}